// Round 1
// baseline (255.889 us; speedup 1.0000x reference)
//
#include <hip/hip_runtime.h>
#include <math.h>

#define N_TOTAL 8192
#define BHALF   4096
#define KDIM    128

// ---------------------------------------------------------------------------
// Kernel A: per-row squared norms; also zero-init T accumulators.
// One wave (64 lanes) per row; each lane holds 2 of the 128 elements.
// ---------------------------------------------------------------------------
__global__ __launch_bounds__(256) void k_sqnorm(const float* __restrict__ F,
                                                float* __restrict__ sq,
                                                float* __restrict__ T) {
    int t = threadIdx.x;
    int row = blockIdx.x * 4 + (t >> 6);
    int lane = t & 63;
    const float* r = F + (size_t)row * KDIM;
    float a = r[lane];
    float b = r[lane + 64];
    float s = fmaf(a, a, b * b);
#pragma unroll
    for (int off = 32; off > 0; off >>= 1) s += __shfl_down(s, off);
    if (lane == 0) {
        sq[row] = s;
        T[row] = 0.0f;
    }
}

// ---------------------------------------------------------------------------
// Kernel B: pairwise Cauchy row-sums over the full 8192x8192 symmetric matrix.
// Tiles 64x64; only tj >= ti computed; off-diagonal tiles scatter both row
// sums (to T[I..]) and col sums (to T[J..]). 256 threads = 16x16, each thread
// owns a 4x4 sub-tile. K=128 staged fully in LDS with an XOR swizzle so the
// float4 fragment reads are (near) conflict-free.
// LDS: As 32KB + Bs 32KB = 64KB; As reused as reduction scratch afterwards.
// ---------------------------------------------------------------------------
__global__ __launch_bounds__(256) void k_pairwise(const float* __restrict__ F,
                                                  const float* __restrict__ sq,
                                                  float* __restrict__ T) {
    int ti = blockIdx.y, tj = blockIdx.x;
    if (tj < ti) return;

    __shared__ __align__(16) float As[64 * 128];
    __shared__ __align__(16) float Bs[64 * 128];

    int t  = threadIdx.x;
    int tx = t & 15;
    int ty = t >> 4;
    int I = ti * 64, J = tj * 64;

    float4*       Asv = (float4*)As;
    float4*       Bsv = (float4*)Bs;
    const float4* Fv  = (const float4*)F;   // row stride = 32 float4

    // Stage tiles: 64 rows x 32 float4 = 2048 float4 each; 8 per thread.
#pragma unroll
    for (int it = 0; it < 8; ++it) {
        int f   = t + it * 256;
        int row = f >> 5;
        int c4  = f & 31;
        int sw  = (row >> 2) & 7;           // XOR swizzle key
        Asv[row * 32 + (c4 ^ sw)] = Fv[(size_t)(I + row) * 32 + c4];
        Bsv[row * 32 + (c4 ^ sw)] = Fv[(size_t)(J + row) * 32 + c4];
    }
    __syncthreads();

    float acc[4][4] = {};
    int swa = ty & 7;
    int swb = tx & 7;
    int ar = ty * 4, br = tx * 4;

#pragma unroll 4
    for (int k4 = 0; k4 < 32; ++k4) {
        float4 a0 = Asv[(ar + 0) * 32 + (k4 ^ swa)];
        float4 a1 = Asv[(ar + 1) * 32 + (k4 ^ swa)];
        float4 a2 = Asv[(ar + 2) * 32 + (k4 ^ swa)];
        float4 a3 = Asv[(ar + 3) * 32 + (k4 ^ swa)];
        float4 b0 = Bsv[(br + 0) * 32 + (k4 ^ swb)];
        float4 b1 = Bsv[(br + 1) * 32 + (k4 ^ swb)];
        float4 b2 = Bsv[(br + 2) * 32 + (k4 ^ swb)];
        float4 b3 = Bsv[(br + 3) * 32 + (k4 ^ swb)];
#define DOT4(ACCV, AV, BV)                          \
        ACCV = fmaf(AV.x, BV.x, ACCV);              \
        ACCV = fmaf(AV.y, BV.y, ACCV);              \
        ACCV = fmaf(AV.z, BV.z, ACCV);              \
        ACCV = fmaf(AV.w, BV.w, ACCV);
        DOT4(acc[0][0], a0, b0) DOT4(acc[0][1], a0, b1) DOT4(acc[0][2], a0, b2) DOT4(acc[0][3], a0, b3)
        DOT4(acc[1][0], a1, b0) DOT4(acc[1][1], a1, b1) DOT4(acc[1][2], a1, b2) DOT4(acc[1][3], a1, b3)
        DOT4(acc[2][0], a2, b0) DOT4(acc[2][1], a2, b1) DOT4(acc[2][2], a2, b2) DOT4(acc[2][3], a2, b3)
        DOT4(acc[3][0], a3, b0) DOT4(acc[3][1], a3, b1) DOT4(acc[3][2], a3, b2) DOT4(acc[3][3], a3, b3)
#undef DOT4
    }
    __syncthreads();   // done with As/Bs contents; As becomes reduction scratch

    // Epilogue: Cauchy transform + row/col partial sums.
    float sqi[4], sqj[4];
#pragma unroll
    for (int d = 0; d < 4; ++d) {
        sqi[d] = sq[I + ar + d];
        sqj[d] = sq[J + br + d];
    }
    float rs[4] = {0.f, 0.f, 0.f, 0.f};
    float cs[4] = {0.f, 0.f, 0.f, 0.f};
#pragma unroll
    for (int di = 0; di < 4; ++di) {
#pragma unroll
        for (int dj = 0; dj < 4; ++dj) {
            float d2 = sqi[di] + sqj[dj] - 2.0f * acc[di][dj];
            d2 = fmaxf(d2, 0.0f);
            float v = 1.0f / (1.0f + d2);   // TEMPERATURE = 1
            rs[di] += v;
            cs[dj] += v;
        }
    }

    float* red = As;   // 64 x 17 scratch (4352 B < 32 KB)

    // Row sums: row (ar+di), contributor tx.
#pragma unroll
    for (int di = 0; di < 4; ++di) red[(ar + di) * 17 + tx] = rs[di];
    __syncthreads();
    if (t < 64) {
        float s = 0.f;
#pragma unroll
        for (int j = 0; j < 16; ++j) s += red[t * 17 + j];
        atomicAdd(&T[I + t], s);
    }
    __syncthreads();

    // Col sums (skip on diagonal tiles: full tile already covered rows).
#pragma unroll
    for (int dj = 0; dj < 4; ++dj) red[(br + dj) * 17 + ty] = cs[dj];
    __syncthreads();
    if (t < 64 && ti != tj) {
        float s = 0.f;
#pragma unroll
        for (int j = 0; j < 16; ++j) s += red[t * 17 + j];
        atomicAdd(&T[J + t], s);
    }
}

// ---------------------------------------------------------------------------
// Kernel C: positive-pair terms, pos_i = log K(z1_i, z2_i) = -log(1+d2).
// One wave per pair.
// ---------------------------------------------------------------------------
__global__ __launch_bounds__(256) void k_pos(const float* __restrict__ F,
                                             const float* __restrict__ sq,
                                             float* __restrict__ posTerm) {
    int t = threadIdx.x;
    int i = blockIdx.x * 4 + (t >> 6);
    int lane = t & 63;
    const float* r1 = F + (size_t)i * KDIM;
    const float* r2 = F + (size_t)(i + BHALF) * KDIM;
    float d = fmaf(r1[lane], r2[lane], r1[lane + 64] * r2[lane + 64]);
#pragma unroll
    for (int off = 32; off > 0; off >>= 1) d += __shfl_down(d, off);
    if (lane == 0) {
        float d2 = sq[i] + sq[i + BHALF] - 2.0f * d;
        d2 = fmaxf(d2, 0.0f);
        posTerm[i] = -logf(1.0f + d2);
    }
}

// ---------------------------------------------------------------------------
// Kernel D: final scalar. loss = sum(log(T-1))/(2b) - sum(posTerm)/b
// ---------------------------------------------------------------------------
__global__ __launch_bounds__(256) void k_final(const float* __restrict__ T,
                                               const float* __restrict__ posTerm,
                                               float* __restrict__ out) {
    int t = threadIdx.x;
    float s1 = 0.f, s2 = 0.f;
    for (int i = t; i < N_TOTAL; i += 256) s1 += logf(T[i] - 1.0f);
    for (int i = t; i < BHALF; i += 256) s2 += posTerm[i];
#pragma unroll
    for (int off = 32; off > 0; off >>= 1) {
        s1 += __shfl_down(s1, off);
        s2 += __shfl_down(s2, off);
    }
    __shared__ float red1[4], red2[4];
    int w = t >> 6, lane = t & 63;
    if (lane == 0) { red1[w] = s1; red2[w] = s2; }
    __syncthreads();
    if (t == 0) {
        float S1 = red1[0] + red1[1] + red1[2] + red1[3];
        float S2 = red2[0] + red2[1] + red2[2] + red2[3];
        out[0] = S1 / (2.0f * (float)BHALF) - S2 / (float)BHALF;
    }
}

// ---------------------------------------------------------------------------
extern "C" void kernel_launch(void* const* d_in, const int* in_sizes, int n_in,
                              void* d_out, int out_size, void* d_ws, size_t ws_size,
                              hipStream_t stream) {
    const float* F = (const float*)d_in[0];
    float* out = (float*)d_out;

    float* wsf     = (float*)d_ws;
    float* sq      = wsf;               // 8192
    float* T       = wsf + N_TOTAL;     // 8192
    float* posTerm = wsf + 2 * N_TOTAL; // 4096

    // A: sq norms + zero T (8192 waves)
    k_sqnorm<<<N_TOTAL / 4, 256, 0, stream>>>(F, sq, T);

    // B: pairwise row sums (upper-triangular tiles of 128x128 tile grid)
    dim3 gridB(N_TOTAL / 64, N_TOTAL / 64);
    k_pairwise<<<gridB, 256, 0, stream>>>(F, sq, T);

    // C: positive pair diag terms (4096 waves)
    k_pos<<<BHALF / 4, 256, 0, stream>>>(F, sq, posTerm);

    // D: final reduction to scalar
    k_final<<<1, 256, 0, stream>>>(T, posTerm, out);
}

// Round 2
// 101.894 us; speedup vs baseline: 2.5113x; 2.5113x over previous
//
#include <hip/hip_runtime.h>
#include <math.h>

#define N_TOTAL 8192
#define BHALF   4096
#define KDIM    128

typedef __bf16 bf16x8 __attribute__((ext_vector_type(8)));
typedef __bf16 bf16x2 __attribute__((ext_vector_type(2)));
typedef float  f32x4  __attribute__((ext_vector_type(4)));

// async global->LDS, 16B per lane; LDS dest must be lane-contiguous.
#define GLOAD_LDS16(GSRC, LDST)                                                \
    __builtin_amdgcn_global_load_lds(                                          \
        (const __attribute__((address_space(1))) void*)(GSRC),                 \
        (__attribute__((address_space(3))) void*)(LDST), 16, 0, 0)

// ---------------------------------------------------------------------------
// Kernel A: fp32 sq-norms (exact), bf16 copy of F, zero T.
// One wave per row; lane l owns elements 2l, 2l+1.
// ---------------------------------------------------------------------------
__global__ __launch_bounds__(256) void k_prep(const float* __restrict__ F,
                                              __bf16* __restrict__ Fbf,
                                              float* __restrict__ sq,
                                              float* __restrict__ T) {
    int t = threadIdx.x;
    int row = blockIdx.x * 4 + (t >> 6);
    int l = t & 63;
    const float2* r = (const float2*)(F + (size_t)row * KDIM);
    float2 v = r[l];
    float s = fmaf(v.x, v.x, v.y * v.y);
#pragma unroll
    for (int off = 32; off > 0; off >>= 1) s += __shfl_down(s, off);
    bf16x2 p;
    p[0] = (__bf16)v.x;
    p[1] = (__bf16)v.y;
    ((bf16x2*)(Fbf + (size_t)row * KDIM))[l] = p;
    if (l == 0) {
        sq[row] = s;
        T[row] = 0.0f;
    }
}

// ---------------------------------------------------------------------------
// Kernel B: MFMA pairwise Cauchy row/col sums, 128x128 tiles, triangular grid.
// 4 waves; wave (wr,wc) owns a 64x64 quadrant as 4x4 fragments of 16x16x32.
// LDS layout: 16B granules, slot(row,g) = row*16 + (g ^ (row&15)); the XOR is
// applied on the GLOBAL side so global_load_lds's lane-contiguous LDS rule
// holds, while fragment ds_read_b128 spreads across all 8 macro-banks.
// ---------------------------------------------------------------------------
__global__ __launch_bounds__(256) void k_pairwise(const __bf16* __restrict__ Fbf,
                                                  const float* __restrict__ sq,
                                                  float* __restrict__ T) {
    // triangular decode: block b -> (ti, tj), tj >= ti, 64x64 tile grid
    int b = blockIdx.x;
    int ti = (int)floorf((129.0f - sqrtf(16641.0f - 8.0f * (float)b)) * 0.5f);
    while (ti * (129 - ti) / 2 > b) --ti;
    while ((ti + 1) * (128 - ti) / 2 <= b) ++ti;
    int tj = ti + (b - ti * (129 - ti) / 2);
    int I = ti * 128, J = tj * 128;
    bool diag = (ti == tj);

    __shared__ __align__(16) __bf16 As[128 * 128];
    __shared__ __align__(16) __bf16 Bs[128 * 128];

    int t = threadIdx.x;
    int w = t >> 6;          // wave 0..3
    int l = t & 63;          // lane
    int wr = w >> 1, wc = w & 1;
    int low = l & 15, kb = l >> 4;

    // ---- stage both tiles (8 granule-iterations x 256 lanes x 16B each) ----
    const __bf16* FA = Fbf + (size_t)I * KDIM;
    const __bf16* FB = Fbf + (size_t)J * KDIM;
#pragma unroll
    for (int it = 0; it < 8; ++it) {
        int f = it * 256 + t;            // granule slot 0..2047
        int row = f >> 4;
        int sg = f & 15;
        int g = sg ^ (row & 15);         // global granule that belongs here
        GLOAD_LDS16(FA + row * KDIM + g * 8, As + (size_t)f * 8);
        GLOAD_LDS16(FB + row * KDIM + g * 8, Bs + (size_t)f * 8);
    }
    __syncthreads();

    // ---- MFMA K-loop: 4 steps of K=32, 4x4 fragments ----
    const bf16x8* Asg = (const bf16x8*)As;   // granule-indexed
    const bf16x8* Bsg = (const bf16x8*)Bs;
    f32x4 acc[4][4] = {};
#pragma unroll
    for (int s = 0; s < 4; ++s) {
        int g = s * 4 + kb;
        bf16x8 aF[4], bF[4];
#pragma unroll
        for (int fr = 0; fr < 4; ++fr) {
            int R = wr * 64 + fr * 16 + low;
            aF[fr] = Asg[R * 16 + (g ^ low)];
        }
#pragma unroll
        for (int fc = 0; fc < 4; ++fc) {
            int C = wc * 64 + fc * 16 + low;
            bF[fc] = Bsg[C * 16 + (g ^ low)];
        }
#pragma unroll
        for (int fr = 0; fr < 4; ++fr)
#pragma unroll
            for (int fc = 0; fc < 4; ++fc)
                acc[fr][fc] = __builtin_amdgcn_mfma_f32_16x16x32_bf16(
                    aF[fr], bF[fc], acc[fr][fc], 0, 0, 0);
    }
    __syncthreads();   // done reading As/Bs; reuse as reduction scratch

    // ---- epilogue: Cauchy + row/col partial sums ----
    // C/D layout: col = low, row = kb*4 + reg   (within each 16x16 fragment)
    float sqi[4][4], sqj[4];
#pragma unroll
    for (int fr = 0; fr < 4; ++fr)
#pragma unroll
        for (int r = 0; r < 4; ++r)
            sqi[fr][r] = sq[I + wr * 64 + fr * 16 + kb * 4 + r];
#pragma unroll
    for (int fc = 0; fc < 4; ++fc)
        sqj[fc] = sq[J + wc * 64 + fc * 16 + low];

    float rowPart[16];
    float colPart[4] = {0.f, 0.f, 0.f, 0.f};
#pragma unroll
    for (int i = 0; i < 16; ++i) rowPart[i] = 0.f;

#pragma unroll
    for (int fr = 0; fr < 4; ++fr) {
#pragma unroll
        for (int fc = 0; fc < 4; ++fc) {
#pragma unroll
            for (int r = 0; r < 4; ++r) {
                float d2 = sqi[fr][r] + sqj[fc] - 2.0f * acc[fr][fc][r];
                d2 = fmaxf(d2, 0.0f);
                float v = __builtin_amdgcn_rcpf(1.0f + d2);
                if (diag && (wr * 64 + fr * 16 + kb * 4 + r) ==
                            (wc * 64 + fc * 16 + low))
                    v = 1.0f;    // exact self-similarity
                rowPart[fr * 4 + r] += v;
                colPart[fc] += v;
            }
        }
    }

    float* rowAcc = (float*)As;   // [128][2]
    float* colAcc = (float*)Bs;   // [128][2]

    // reduce row partials across the 16 lanes sharing a row (low bits)
#pragma unroll
    for (int i = 0; i < 16; ++i) {
        float x = rowPart[i];
        x += __shfl_xor(x, 1);
        x += __shfl_xor(x, 2);
        x += __shfl_xor(x, 4);
        x += __shfl_xor(x, 8);
        rowPart[i] = x;
    }
    if (low == 0) {
#pragma unroll
        for (int fr = 0; fr < 4; ++fr)
#pragma unroll
            for (int r = 0; r < 4; ++r)
                rowAcc[(wr * 64 + fr * 16 + kb * 4 + r) * 2 + wc] =
                    rowPart[fr * 4 + r];
    }

    // reduce col partials across the 4 lane-quads (kb)
#pragma unroll
    for (int c = 0; c < 4; ++c) {
        float x = colPart[c];
        x += __shfl_xor(x, 16);
        x += __shfl_xor(x, 32);
        colPart[c] = x;
    }
    if (kb == 0) {
#pragma unroll
        for (int fc = 0; fc < 4; ++fc)
            colAcc[(wc * 64 + fc * 16 + low) * 2 + wr] = colPart[fc];
    }
    __syncthreads();

    if (t < 128) {
        atomicAdd(&T[I + t], rowAcc[t * 2] + rowAcc[t * 2 + 1]);
    } else if (!diag) {
        int c = t - 128;
        atomicAdd(&T[J + c], colAcc[c * 2] + colAcc[c * 2 + 1]);
    }
}

// ---------------------------------------------------------------------------
// Kernel C: positive-pair terms (fp32 exact), one wave per pair.
// ---------------------------------------------------------------------------
__global__ __launch_bounds__(256) void k_pos(const float* __restrict__ F,
                                             const float* __restrict__ sq,
                                             float* __restrict__ posTerm) {
    int t = threadIdx.x;
    int i = blockIdx.x * 4 + (t >> 6);
    int lane = t & 63;
    const float* r1 = F + (size_t)i * KDIM;
    const float* r2 = F + (size_t)(i + BHALF) * KDIM;
    float d = fmaf(r1[lane], r2[lane], r1[lane + 64] * r2[lane + 64]);
#pragma unroll
    for (int off = 32; off > 0; off >>= 1) d += __shfl_down(d, off);
    if (lane == 0) {
        float d2 = sq[i] + sq[i + BHALF] - 2.0f * d;
        d2 = fmaxf(d2, 0.0f);
        posTerm[i] = -logf(1.0f + d2);
    }
}

// ---------------------------------------------------------------------------
// Kernel D: final scalar. loss = sum(log(T-1))/(2b) - sum(posTerm)/b
// ---------------------------------------------------------------------------
__global__ __launch_bounds__(256) void k_final(const float* __restrict__ T,
                                               const float* __restrict__ posTerm,
                                               float* __restrict__ out) {
    int t = threadIdx.x;
    float s1 = 0.f, s2 = 0.f;
    for (int i = t; i < N_TOTAL; i += 256) s1 += logf(T[i] - 1.0f);
    for (int i = t; i < BHALF; i += 256) s2 += posTerm[i];
#pragma unroll
    for (int off = 32; off > 0; off >>= 1) {
        s1 += __shfl_down(s1, off);
        s2 += __shfl_down(s2, off);
    }
    __shared__ float red1[4], red2[4];
    int w = t >> 6, lane = t & 63;
    if (lane == 0) { red1[w] = s1; red2[w] = s2; }
    __syncthreads();
    if (t == 0) {
        float S1 = red1[0] + red1[1] + red1[2] + red1[3];
        float S2 = red2[0] + red2[1] + red2[2] + red2[3];
        out[0] = S1 / (2.0f * (float)BHALF) - S2 / (float)BHALF;
    }
}

// ---------------------------------------------------------------------------
extern "C" void kernel_launch(void* const* d_in, const int* in_sizes, int n_in,
                              void* d_out, int out_size, void* d_ws, size_t ws_size,
                              hipStream_t stream) {
    const float* F = (const float*)d_in[0];
    float* out = (float*)d_out;

    char* ws = (char*)d_ws;
    __bf16* Fbf    = (__bf16*)ws;                              // 2 MB
    float*  sq     = (float*)(ws + (size_t)N_TOTAL * KDIM * 2);
    float*  T      = sq + N_TOTAL;
    float*  posTerm = T + N_TOTAL;

    k_prep<<<N_TOTAL / 4, 256, 0, stream>>>(F, Fbf, sq, T);

    int nTiles = N_TOTAL / 128;                  // 64
    int nBlocks = nTiles * (nTiles + 1) / 2;     // 2080 triangular tiles
    k_pairwise<<<nBlocks, 256, 0, stream>>>(Fbf, sq, T);

    k_pos<<<BHALF / 4, 256, 0, stream>>>(F, sq, posTerm);

    k_final<<<1, 256, 0, stream>>>(T, posTerm, out);
}

// Round 3
// 98.395 us; speedup vs baseline: 2.6006x; 1.0356x over previous
//
#include <hip/hip_runtime.h>
#include <math.h>

#define N_TOTAL 8192
#define BHALF   4096
#define KDIM    128

typedef __bf16 bf16x8 __attribute__((ext_vector_type(8)));
typedef __bf16 bf16x2 __attribute__((ext_vector_type(2)));
typedef float  f32x4  __attribute__((ext_vector_type(4)));

// async global->LDS, 16B per lane; LDS dest must be lane-contiguous.
#define GLOAD_LDS16(GSRC, LDST)                                                \
    __builtin_amdgcn_global_load_lds(                                          \
        (const __attribute__((address_space(1))) void*)(GSRC),                 \
        (__attribute__((address_space(3))) void*)(LDST), 16, 0, 0)

// ---------------------------------------------------------------------------
// Kernel A (fused prep+pos): one wave per pair (i, i+BHALF).
//  - fp32 sq-norms for both rows (exact), bf16 copy of both rows, zero T,
//  - positive-pair term atomicAdd'ed straight into out[0]:
//      loss = sum(log(T-1))/(2b) + sum(log(1+d2_pos))/b   (linear fold)
// ---------------------------------------------------------------------------
__global__ __launch_bounds__(256) void k_prep_pos(const float* __restrict__ F,
                                                  __bf16* __restrict__ Fbf,
                                                  float* __restrict__ sq,
                                                  float* __restrict__ T,
                                                  float* __restrict__ out) {
    int t = threadIdx.x;
    int w = t >> 6, l = t & 63;
    int p = blockIdx.x * 4 + w;          // pair index 0..4095
    const float2* r1 = (const float2*)(F + (size_t)p * KDIM);
    const float2* r2 = (const float2*)(F + (size_t)(p + BHALF) * KDIM);
    float2 a = r1[l];
    float2 c = r2[l];

    float s1 = fmaf(a.x, a.x, a.y * a.y);
    float s2 = fmaf(c.x, c.x, c.y * c.y);
    float dp = fmaf(a.x, c.x, a.y * c.y);
#pragma unroll
    for (int off = 32; off > 0; off >>= 1) {
        s1 += __shfl_down(s1, off);
        s2 += __shfl_down(s2, off);
        dp += __shfl_down(dp, off);
    }

    bf16x2 pa, pc;
    pa[0] = (__bf16)a.x; pa[1] = (__bf16)a.y;
    pc[0] = (__bf16)c.x; pc[1] = (__bf16)c.y;
    ((bf16x2*)(Fbf + (size_t)p * KDIM))[l] = pa;
    ((bf16x2*)(Fbf + (size_t)(p + BHALF) * KDIM))[l] = pc;

    __shared__ float posRed[4];
    if (l == 0) {
        sq[p] = s1;
        sq[p + BHALF] = s2;
        T[p] = 0.0f;
        T[p + BHALF] = 0.0f;
        float d2 = fmaxf(s1 + s2 - 2.0f * dp, 0.0f);
        posRed[w] = logf(1.0f + d2);
    }
    __syncthreads();
    if (t == 0) {
        float s = posRed[0] + posRed[1] + posRed[2] + posRed[3];
        atomicAdd(out, s / (float)BHALF);
    }
}

// ---------------------------------------------------------------------------
// Kernel B: MFMA pairwise Cauchy row/col sums, 128x128 tiles, triangular grid.
// 512 threads = 8 waves in a 4x2 grid; each wave owns 32 rows x 64 cols as
// 2x4 fragments of mfma_f32_16x16x32_bf16. 16-B-granule XOR swizzle applied
// on the GLOBAL side of global_load_lds (LDS dest stays lane-contiguous);
// fragment ds_read_b128s then spread evenly over all LDS macro-banks.
// Separate 3 KB reduction scratch -> only 2 barriers total.
// ---------------------------------------------------------------------------
__global__ __launch_bounds__(512, 4) void k_pairwise(
        const __bf16* __restrict__ Fbf,
        const float* __restrict__ sq,
        float* __restrict__ T) {
    // triangular decode: block b -> (ti, tj), tj >= ti, 64x64 tile grid
    int b = blockIdx.x;
    int ti = (int)floorf((129.0f - sqrtf(16641.0f - 8.0f * (float)b)) * 0.5f);
    while (ti * (129 - ti) / 2 > b) --ti;
    while ((ti + 1) * (128 - ti) / 2 <= b) ++ti;
    int tj = ti + (b - ti * (129 - ti) / 2);
    int I = ti * 128, J = tj * 128;
    bool diag = (ti == tj);

    __shared__ __align__(16) __bf16 As[128 * 128];
    __shared__ __align__(16) __bf16 Bs[128 * 128];
    __shared__ float rowAcc[128][2];
    __shared__ float colAcc[128][4];

    int t = threadIdx.x;
    int w = t >> 6;              // wave 0..7
    int l = t & 63;
    int wr = w >> 1, wc = w & 1; // 4x2 wave grid
    int low = l & 15, kb = l >> 4;

    // ---- stage both 128x128 bf16 tiles (2048 granules each) ----
    const __bf16* FA = Fbf + (size_t)I * KDIM;
    const __bf16* FB = Fbf + (size_t)J * KDIM;
#pragma unroll
    for (int it = 0; it < 4; ++it) {
        int f = it * 512 + t;            // granule slot 0..2047
        int row = f >> 4;
        int sg = f & 15;
        int g = sg ^ (row & 15);         // global granule that lands here
        GLOAD_LDS16(FA + row * KDIM + g * 8, As + (size_t)f * 8);
        GLOAD_LDS16(FB + row * KDIM + g * 8, Bs + (size_t)f * 8);
    }
    __syncthreads();

    // ---- MFMA K-loop: 4 steps of K=32, 2x4 fragments per wave ----
    const bf16x8* Asg = (const bf16x8*)As;
    const bf16x8* Bsg = (const bf16x8*)Bs;
    f32x4 acc[2][4] = {};
#pragma unroll
    for (int s = 0; s < 4; ++s) {
        int g = s * 4 + kb;
        bf16x8 aF[2], bF[4];
#pragma unroll
        for (int fr = 0; fr < 2; ++fr) {
            int R = wr * 32 + fr * 16 + low;
            aF[fr] = Asg[R * 16 + (g ^ low)];
        }
#pragma unroll
        for (int fc = 0; fc < 4; ++fc) {
            int C = wc * 64 + fc * 16 + low;
            bF[fc] = Bsg[C * 16 + (g ^ low)];
        }
#pragma unroll
        for (int fr = 0; fr < 2; ++fr)
#pragma unroll
            for (int fc = 0; fc < 4; ++fc)
                acc[fr][fc] = __builtin_amdgcn_mfma_f32_16x16x32_bf16(
                    aF[fr], bF[fc], acc[fr][fc], 0, 0, 0);
    }

    // ---- epilogue: Cauchy + row/col partial sums ----
    // C/D layout: col = low, row = kb*4 + reg (within each 16x16 fragment)
    float sqi[2][4], sqj[4];
#pragma unroll
    for (int fr = 0; fr < 2; ++fr)
#pragma unroll
        for (int r = 0; r < 4; ++r)
            sqi[fr][r] = sq[I + wr * 32 + fr * 16 + kb * 4 + r];
#pragma unroll
    for (int fc = 0; fc < 4; ++fc)
        sqj[fc] = sq[J + wc * 64 + fc * 16 + low];

    float rowPart[2][4] = {};
    float colPart[4] = {0.f, 0.f, 0.f, 0.f};
#pragma unroll
    for (int fr = 0; fr < 2; ++fr) {
#pragma unroll
        for (int fc = 0; fc < 4; ++fc) {
#pragma unroll
            for (int r = 0; r < 4; ++r) {
                float d2 = sqi[fr][r] + sqj[fc] - 2.0f * acc[fr][fc][r];
                d2 = fmaxf(d2, 0.0f);
                float v = __builtin_amdgcn_rcpf(1.0f + d2);
                rowPart[fr][r] += v;
                colPart[fc] += v;
            }
        }
    }

    // row partials: reduce across the 16 lanes sharing a row (low)
#pragma unroll
    for (int fr = 0; fr < 2; ++fr)
#pragma unroll
        for (int r = 0; r < 4; ++r) {
            float x = rowPart[fr][r];
            x += __shfl_xor(x, 1);
            x += __shfl_xor(x, 2);
            x += __shfl_xor(x, 4);
            x += __shfl_xor(x, 8);
            if (low == 0)
                rowAcc[wr * 32 + fr * 16 + kb * 4 + r][wc] = x;
        }

    // col partials: reduce across the 4 lane-quads (kb)
#pragma unroll
    for (int fc = 0; fc < 4; ++fc) {
        float x = colPart[fc];
        x += __shfl_xor(x, 16);
        x += __shfl_xor(x, 32);
        if (kb == 0)
            colAcc[wc * 64 + fc * 16 + low][wr] = x;
    }
    __syncthreads();

    if (t < 128) {
        atomicAdd(&T[I + t], rowAcc[t][0] + rowAcc[t][1]);
    } else if (t < 256 && !diag) {
        int c = t - 128;
        atomicAdd(&T[J + c],
                  colAcc[c][0] + colAcc[c][1] + colAcc[c][2] + colAcc[c][3]);
    }
}

// ---------------------------------------------------------------------------
// Kernel C: neg term. 32 blocks x 256 threads; each thread one T entry;
// block-reduce; one atomicAdd into out per block.
// ---------------------------------------------------------------------------
__global__ __launch_bounds__(256) void k_final(const float* __restrict__ T,
                                               float* __restrict__ out) {
    int t = threadIdx.x;
    int i = blockIdx.x * 256 + t;
    float s = logf(T[i] - 1.0f);
#pragma unroll
    for (int off = 32; off > 0; off >>= 1) s += __shfl_down(s, off);
    __shared__ float red[4];
    int w = t >> 6, l = t & 63;
    if (l == 0) red[w] = s;
    __syncthreads();
    if (t == 0) {
        float S = red[0] + red[1] + red[2] + red[3];
        atomicAdd(out, S / (2.0f * (float)BHALF));
    }
}

// ---------------------------------------------------------------------------
extern "C" void kernel_launch(void* const* d_in, const int* in_sizes, int n_in,
                              void* d_out, int out_size, void* d_ws, size_t ws_size,
                              hipStream_t stream) {
    const float* F = (const float*)d_in[0];
    float* out = (float*)d_out;

    char* ws = (char*)d_ws;
    __bf16* Fbf = (__bf16*)ws;                               // 2 MB
    float*  sq  = (float*)(ws + (size_t)N_TOTAL * KDIM * 2);
    float*  T   = sq + N_TOTAL;

    hipMemsetAsync(out, 0, sizeof(float), stream);

    k_prep_pos<<<BHALF / 4, 256, 0, stream>>>(F, Fbf, sq, T, out);

    int nTiles = N_TOTAL / 128;                  // 64
    int nBlocks = nTiles * (nTiles + 1) / 2;     // 2080 triangular tiles
    k_pairwise<<<nBlocks, 512, 0, stream>>>(Fbf, sq, T);

    k_final<<<N_TOTAL / 256, 256, 0, stream>>>(T, out);
}